// Round 6
// baseline (637.283 us; speedup 1.0000x reference)
//
#include <hip/hip_runtime.h>

#define N_NODES 50000
#define N_EDGES 100000
#define DD 32
#define STEPS 5
#define ETYPES 8
#define CAP_T 13312              // per-type slot capacity (mult of 64; mean 12500, sigma~105)
#define CAP (ETYPES * CAP_T)     // 106496 sorted slots
#define TRASH N_EDGES            // trash row index in fea arrays (extra row allocated)
#define SCAN_B 49                // 49 blocks * 1024 = 50176 >= N_NODES

#define NPB 32           // nodes per block (gru): 1563 blocks -> 6.1 waves/SIMD
#define CAT_STRIDE 68    // floats per cat row: 64 (in|out) + 4 pad -> 17 float4

// prop[n,j] = emb[token[n],j]; zero cnt_in/cnt_out/tcnt; dummy-init sorted slots.
__global__ void init_kernel(const int* __restrict__ token,
                            const float* __restrict__ emb,
                            float* __restrict__ prop,
                            int* __restrict__ cnt,      // 2N+8: cnt_in | cnt_out | tcnt
                            int* __restrict__ se,
                            int* __restrict__ spi,
                            int* __restrict__ spo) {
    int idx = blockIdx.x * 256 + threadIdx.x;   // over N*D = 1.6M, exact grid
    int n = idx >> 5, j = idx & 31;
    prop[idx] = emb[token[n] * DD + j];
    if (idx < 2 * N_NODES + ETYPES) cnt[idx] = 0;
    if (idx < CAP) { se[idx] = 0; spi[idx] = TRASH; spo[idx] = TRASH; }
}

// One pass over edges: per-node ranks (global atomics) + type-bucket slot via
// block-local LDS histogram (one global atomic per type per block for the base).
__global__ void hist_kernel(const int* __restrict__ etype,
                            const int* __restrict__ src,
                            const int* __restrict__ dst,
                            int* __restrict__ cnt_in, int* __restrict__ cnt_out,
                            int* __restrict__ tcnt,
                            int* __restrict__ rank_in, int* __restrict__ rank_out,
                            int* __restrict__ qe) {
    __shared__ int lh[ETYPES], lbase[ETYPES];
    int tid = threadIdx.x;
    int e = blockIdx.x * 256 + tid;
    if (tid < ETYPES) lh[tid] = 0;
    __syncthreads();
    int t = 0, lr = 0;
    bool v = e < N_EDGES;
    if (v) {
        t = etype[e];
        lr = atomicAdd(&lh[t], 1);
        rank_in[e]  = atomicAdd(&cnt_in[dst[e]], 1);
        rank_out[e] = atomicAdd(&cnt_out[src[e]], 1);
    }
    __syncthreads();
    if (tid < ETYPES) lbase[tid] = atomicAdd(&tcnt[tid], lh[tid]);
    __syncthreads();
    if (v) qe[e] = t * CAP_T + lbase[t] + lr;
}

// Hierarchical scan stage 1: block-local exclusive scan (coalesced, wide).
__global__ __launch_bounds__(1024) void
scan1(const int* __restrict__ cnt_in, const int* __restrict__ cnt_out,
      int* __restrict__ off_in, int* __restrict__ off_out,
      int* __restrict__ bsum) {
    __shared__ int s[1024];
    int b = blockIdx.x;
    int ab = (b < SCAN_B) ? b : b - SCAN_B;
    const int* a = (b < SCAN_B) ? cnt_in : cnt_out;
    int* o = (b < SCAN_B) ? off_in : off_out;
    int i = ab * 1024 + threadIdx.x;
    int x = (i < N_NODES) ? a[i] : 0;
    s[threadIdx.x] = x;
    __syncthreads();
    for (int ofs = 1; ofs < 1024; ofs <<= 1) {
        int u = (threadIdx.x >= ofs) ? s[threadIdx.x - ofs] : 0;
        __syncthreads();
        s[threadIdx.x] += u;
        __syncthreads();
    }
    if (i < N_NODES) o[i] = s[threadIdx.x] - x;   // local exclusive
    if (threadIdx.x == 1023) bsum[b] = s[1023];
}

// Stage 2: scan 98 block sums. Since sum(cnt_in)=sum(cnt_out)=E exactly, one
// combined scan with a constant -E correction splits the two arrays.
__global__ void scan2(const int* __restrict__ bsum, int* __restrict__ ebase,
                      int* __restrict__ off_in, int* __restrict__ off_out) {
    __shared__ int s[128];
    int t = threadIdx.x;
    int x = (t < 2 * SCAN_B) ? bsum[t] : 0;
    s[t] = x;
    __syncthreads();
    for (int ofs = 1; ofs < 128; ofs <<= 1) {
        int u = (t >= ofs) ? s[t - ofs] : 0;
        __syncthreads();
        s[t] += u;
        __syncthreads();
    }
    if (t < SCAN_B) ebase[t] = s[t] - x;
    else if (t < 2 * SCAN_B) ebase[t] = s[t] - x - N_EDGES;
    if (t == 0) { off_in[N_NODES] = N_EDGES; off_out[N_NODES] = N_EDGES; }
}

// Stage 3: add scanned block bases.
__global__ __launch_bounds__(1024) void
scan3(int* __restrict__ off_in, int* __restrict__ off_out,
      const int* __restrict__ ebase) {
    int b = blockIdx.x;
    int ab = (b < SCAN_B) ? b : b - SCAN_B;
    int* o = (b < SCAN_B) ? off_in : off_out;
    int i = ab * 1024 + threadIdx.x;
    if (i < N_NODES) o[i] += ebase[b];
}

// Scatter edge records into type-sorted slots with final CSR positions; also
// record the owning node of every CSR row for the gru flat-stream gather.
__global__ void place_kernel(const int* __restrict__ src,
                             const int* __restrict__ dst,
                             const int* __restrict__ in_off,
                             const int* __restrict__ out_off,
                             const int* __restrict__ rank_in,
                             const int* __restrict__ rank_out,
                             const int* __restrict__ qe,
                             int* __restrict__ se, int* __restrict__ spi,
                             int* __restrict__ spo,
                             int* __restrict__ node_in,
                             int* __restrict__ node_out) {
    int e = blockIdx.x * 256 + threadIdx.x;
    if (e < N_EDGES) {
        int q = qe[e];
        int pi = in_off[dst[e]]  + rank_in[e];
        int po = out_off[src[e]] + rank_out[e];
        node_in[pi]  = dst[e];
        node_out[po] = src[e];
        if (q < CAP) {                          // guard: never OOB even on 8-sigma
            se[q]  = src[e];
            spi[q] = pi;
            spo[q] = po;
        }
    }
}

// Wave = 16 same-type edges (two half-waves of 8). W column j lives in 64 VGPRs
// per lane for the whole wave: zero weight memory traffic in the inner loop.
__global__ __launch_bounds__(256) void
edge_kernel(const int* __restrict__ se, const int* __restrict__ spi,
            const int* __restrict__ spo, const float* __restrict__ W_edge,
            const float* __restrict__ prop,
            float* __restrict__ fea_in, float* __restrict__ fea_out) {
    int wid = blockIdx.x * 4 + (threadIdx.x >> 6);
    int lane = threadIdx.x & 63;
    int j = lane & 31;
    int slot0 = wid * 16 + ((lane >> 5) << 3);     // this half-wave's 8 slots
    int type = (wid * 16) / CAP_T;                 // wave-uniform (CAP_T % 16 == 0)
    const float2* Wt = (const float2*)W_edge + (size_t)type * (DD * DD);
    float2 w[DD];
#pragma unroll
    for (int i = 0; i < DD; ++i) w[i] = Wt[i * DD + j];   // 8KB once per wave
    int s[8], pi[8], po[8];
    float h[8];
#pragma unroll
    for (int k = 0; k < 8; ++k) {
        s[k] = se[slot0 + k]; pi[k] = spi[slot0 + k]; po[k] = spo[slot0 + k];
    }
#pragma unroll
    for (int k = 0; k < 8; ++k) h[k] = prop[(size_t)s[k] * DD + j];
    float aF[8] = {0.f,0.f,0.f,0.f,0.f,0.f,0.f,0.f};
    float aR[8] = {0.f,0.f,0.f,0.f,0.f,0.f,0.f,0.f};
#pragma unroll
    for (int i = 0; i < DD; ++i) {
#pragma unroll
        for (int k = 0; k < 8; ++k) {
            float hi = __shfl(h[k], i, 32);        // broadcast within half-wave
            aF[k] = fmaf(hi, w[i].x, aF[k]);
            aR[k] = fmaf(hi, w[i].y, aR[k]);
        }
    }
#pragma unroll
    for (int k = 0; k < 8; ++k) {
        fea_in [(size_t)pi[k] * DD + j] = aF[k];   // plain 128B-row stores
        fea_out[(size_t)po[k] * DD + j] = aR[k];
    }
}

__device__ __forceinline__ void fma4(float (&acc)[4], float c, const float4& w) {
    acc[0] = fmaf(c, w.x, acc[0]);
    acc[1] = fmaf(c, w.y, acc[1]);
    acc[2] = fmaf(c, w.z, acc[2]);
    acc[3] = fmaf(c, w.w, acc[3]);
}
__device__ __forceinline__ float sigm(float x) {
    return 1.f / (1.f + __expf(-x));
}
__device__ __forceinline__ float fast_tanh(float x) {
    x = fminf(fmaxf(x, -15.f), 15.f);
    float e = __expf(2.f * x);
    return (e - 1.f) / (e + 1.f);
}

// Block = 256 threads = 32 nodes (NPT=1). 1563 blocks -> ~6 waves/SIMD for
// latency hiding (round-5 failure was grid starvation: 391 blocks = 1.5/SIMD).
// cat LDS = 8.7 KB (in|out only); prop in registers; prop & r*p matvec
// contributions broadcast via __shfl(.,i2,8). 2 __syncthreads total.
__global__ __launch_bounds__(256, 6) void
gru_kernel(const float* __restrict__ W_r, const float* __restrict__ b_r,
           const float* __restrict__ W_z, const float* __restrict__ b_z,
           const float* __restrict__ W_t, const float* __restrict__ b_t,
           const float* __restrict__ fea_in,
           const float* __restrict__ fea_out,
           const int* __restrict__ in_off,
           const int* __restrict__ out_off,
           const int* __restrict__ node_in,
           const int* __restrict__ node_out,
           float* __restrict__ prop,
           float* __restrict__ out2) {
    __shared__ float cat[NPB * CAT_STRIDE];           // 8.7 KB
    float4* cat4 = (float4*)cat;                      // row stride 17 float4
    const int tid = threadIdx.x;
    const int n0 = blockIdx.x * NPB;
    const int nhi = min(n0 + NPB, N_NODES);
    const int jq = tid & 7;
    const int ng = tid >> 3;

    // ---- zero in/out slots (NPB*17 = 544 float4) ----
    {
        const float4 zz = {0.f, 0.f, 0.f, 0.f};
#pragma unroll
        for (int q = 0; q < 3; ++q) {
            int i = q * 256 + tid;
            if (i < NPB * 17) cat4[i] = zz;
        }
    }
    // ---- prop -> registers (thread mapping == matvec mapping) ----
    float p_[4];
    {
        const float4* p4 = (const float4*)(prop + (size_t)n0 * DD);
        const float4 zz = {0.f, 0.f, 0.f, 0.f};
        float4 p = (n0 + ng < N_NODES) ? p4[tid] : zz;
        p_[0] = p.x; p_[1] = p.y; p_[2] = p.z; p_[3] = p.w;
    }
    __syncthreads();

    // ---- flat-stream the block's CSR row ranges into cat via LDS atomics ----
    {
        const float4* fi4 = (const float4*)fea_in;    // row = 8 float4
        const float4* fo4 = (const float4*)fea_out;
        int r0 = in_off[n0], r1 = in_off[nhi];
        for (int idx = r0 * 8 + tid; idx < r1 * 8; idx += 256) {
            int row = idx >> 3, c4 = idx & 7;
            float4 v = fi4[idx];                      // coalesced stream
            int local = node_in[row] - n0;
            float* b = &cat[local * CAT_STRIDE + c4 * 4];
            atomicAdd(b + 0, v.x); atomicAdd(b + 1, v.y);
            atomicAdd(b + 2, v.z); atomicAdd(b + 3, v.w);
        }
        int s0 = out_off[n0], s1 = out_off[nhi];
        for (int idx = s0 * 8 + tid; idx < s1 * 8; idx += 256) {
            int row = idx >> 3, c4 = idx & 7;
            float4 v = fo4[idx];
            int local = node_out[row] - n0;
            float* b = &cat[local * CAT_STRIDE + 32 + c4 * 4];
            atomicAdd(b + 0, v.x); atomicAdd(b + 1, v.y);
            atomicAdd(b + 2, v.z); atomicAdd(b + 3, v.w);
        }
    }
    __syncthreads();

    // ---- phase A: r,z ----
    float r_[4], z_[4];
    {
        float4 br = ((const float4*)b_r)[jq];
        float4 bz = ((const float4*)b_z)[jq];
        r_[0] = br.x; r_[1] = br.y; r_[2] = br.z; r_[3] = br.w;
        z_[0] = bz.x; z_[1] = bz.y; z_[2] = bz.z; z_[3] = bz.w;
    }
    // rows 0..63: in|out from LDS
#pragma unroll 1
    for (int g = 0; g < 16; ++g) {
        int m0 = g * 4;
        float4 wr[4], wz[4];
#pragma unroll
        for (int i = 0; i < 4; ++i) {
            wr[i] = ((const float4*)(W_r + (m0 + i) * DD))[jq];
            wz[i] = ((const float4*)(W_z + (m0 + i) * DD))[jq];
        }
        float4 c = cat4[ng * 17 + g];
        fma4(r_, c.x, wr[0]); fma4(r_, c.y, wr[1]);
        fma4(r_, c.z, wr[2]); fma4(r_, c.w, wr[3]);
        fma4(z_, c.x, wz[0]); fma4(z_, c.y, wz[1]);
        fma4(z_, c.z, wz[2]); fma4(z_, c.w, wz[3]);
    }
    // rows 64..95: prop via 8-lane shfl broadcast
#pragma unroll 1
    for (int i2 = 0; i2 < 8; ++i2) {
        float4 wr[4], wz[4];
#pragma unroll
        for (int c = 0; c < 4; ++c) {
            wr[c] = ((const float4*)(W_r + (64 + i2 * 4 + c) * DD))[jq];
            wz[c] = ((const float4*)(W_z + (64 + i2 * 4 + c) * DD))[jq];
        }
        float pc0 = __shfl(p_[0], i2, 8);
        float pc1 = __shfl(p_[1], i2, 8);
        float pc2 = __shfl(p_[2], i2, 8);
        float pc3 = __shfl(p_[3], i2, 8);
        fma4(r_, pc0, wr[0]); fma4(r_, pc1, wr[1]);
        fma4(r_, pc2, wr[2]); fma4(r_, pc3, wr[3]);
        fma4(z_, pc0, wz[0]); fma4(z_, pc1, wz[1]);
        fma4(z_, pc2, wz[2]); fma4(z_, pc3, wz[3]);
    }

#pragma unroll
    for (int j = 0; j < 4; ++j) {
        r_[j] = sigm(r_[j]) * p_[j];                  // r := r*p
        z_[j] = sigm(z_[j]);
    }

    // ---- phase B: t ----
    float t_[4];
    {
        float4 bt = ((const float4*)b_t)[jq];
        t_[0] = bt.x; t_[1] = bt.y; t_[2] = bt.z; t_[3] = bt.w;
    }
#pragma unroll 1
    for (int g = 0; g < 16; ++g) {
        int m0 = g * 4;
        float4 wt[4];
#pragma unroll
        for (int i = 0; i < 4; ++i)
            wt[i] = ((const float4*)(W_t + (m0 + i) * DD))[jq];
        float4 c = cat4[ng * 17 + g];
        fma4(t_, c.x, wt[0]); fma4(t_, c.y, wt[1]);
        fma4(t_, c.z, wt[2]); fma4(t_, c.w, wt[3]);
    }
    // rows 64..95: r*p via 8-lane shfl broadcast
#pragma unroll 1
    for (int i2 = 0; i2 < 8; ++i2) {
        float4 wt[4];
#pragma unroll
        for (int c = 0; c < 4; ++c)
            wt[c] = ((const float4*)(W_t + (64 + i2 * 4 + c) * DD))[jq];
        float rc0 = __shfl(r_[0], i2, 8);
        float rc1 = __shfl(r_[1], i2, 8);
        float rc2 = __shfl(r_[2], i2, 8);
        float rc3 = __shfl(r_[3], i2, 8);
        fma4(t_, rc0, wt[0]); fma4(t_, rc1, wt[1]);
        fma4(t_, rc2, wt[2]); fma4(t_, rc3, wt[3]);
    }

    // ---- update: prop = p + z*(tanh(t) - p); final step also writes out2 ----
    int node = n0 + ng;
    if (node < N_NODES) {
        float4 o;
        o.x = fmaf(z_[0], fast_tanh(t_[0]) - p_[0], p_[0]);
        o.y = fmaf(z_[1], fast_tanh(t_[1]) - p_[1], p_[1]);
        o.z = fmaf(z_[2], fast_tanh(t_[2]) - p_[2], p_[2]);
        o.w = fmaf(z_[3], fast_tanh(t_[3]) - p_[3], p_[3]);
        ((float4*)(prop + (size_t)node * DD))[jq] = o;
        if (out2) ((float4*)(out2 + (size_t)node * DD))[jq] = o;
    }
}

extern "C" void kernel_launch(void* const* d_in, const int* in_sizes, int n_in,
                              void* d_out, int out_size, void* d_ws, size_t ws_size,
                              hipStream_t stream) {
    const int*   token  = (const int*)d_in[0];
    const int*   etype  = (const int*)d_in[1];
    const int*   src    = (const int*)d_in[2];
    const int*   dst    = (const int*)d_in[3];
    const float* emb    = (const float*)d_in[4];
    const float* W_edge = (const float*)d_in[5];
    const float* W_r    = (const float*)d_in[6];
    const float* b_r    = (const float*)d_in[7];
    const float* W_z    = (const float*)d_in[8];
    const float* b_z    = (const float*)d_in[9];
    const float* W_t    = (const float*)d_in[10];
    const float* b_t    = (const float*)d_in[11];
    float* out = (float*)d_out;

    // Persistent workspace (~34.5 MB; ws_size = 256 MB per the poison fill):
    float* prop    = (float*)d_ws;                            // N*D
    float* fea_in  = prop    + (size_t)N_NODES * DD;          // (E+1)*D
    float* fea_out = fea_in  + (size_t)(N_EDGES + 1) * DD;    // (E+1)*D
    int* in_off   = (int*)(fea_out + (size_t)(N_EDGES + 1) * DD); // N+1
    int* out_off  = in_off + (N_NODES + 1);                   // N+1
    int* se       = out_off + (N_NODES + 1);                  // CAP
    int* spi      = se + CAP;                                 // CAP
    int* spo      = spi + CAP;                                // CAP
    int* node_in  = spo + CAP;                                // E
    int* node_out = node_in + N_EDGES;                        // E

    // Setup temporaries OVERLAID on fea_in (dead before first edge_kernel
    // write; step loop never reads them).
    int* cnt      = (int*)fea_in;                             // 2N+8
    int* cnt_in   = cnt;
    int* cnt_out  = cnt + N_NODES;
    int* tcnt     = cnt + 2 * N_NODES;
    int* rank_in  = cnt + 2 * N_NODES + ETYPES;               // E
    int* rank_out = rank_in + N_EDGES;                        // E
    int* qe       = rank_out + N_EDGES;                       // E
    int* bsum     = qe + N_EDGES;                             // 2*SCAN_B
    int* ebase    = bsum + 2 * SCAN_B;                        // 2*SCAN_B

    // per-launch setup: prop init + type-bucketed CSR build
    init_kernel<<<(N_NODES * DD) / 256, 256, 0, stream>>>(token, emb, prop, cnt,
                                                          se, spi, spo);
    hist_kernel<<<(N_EDGES + 255) / 256, 256, 0, stream>>>(
        etype, src, dst, cnt_in, cnt_out, tcnt, rank_in, rank_out, qe);
    scan1<<<2 * SCAN_B, 1024, 0, stream>>>(cnt_in, cnt_out, in_off, out_off, bsum);
    scan2<<<1, 128, 0, stream>>>(bsum, ebase, in_off, out_off);
    scan3<<<2 * SCAN_B, 1024, 0, stream>>>(in_off, out_off, ebase);
    place_kernel<<<(N_EDGES + 255) / 256, 256, 0, stream>>>(
        src, dst, in_off, out_off, rank_in, rank_out, qe, se, spi, spo,
        node_in, node_out);

    for (int step = 0; step < STEPS; ++step) {
        edge_kernel<<<CAP / 64, 256, 0, stream>>>(se, spi, spo, W_edge, prop,
                                                  fea_in, fea_out);
        gru_kernel<<<(N_NODES + NPB - 1) / NPB, 256, 0, stream>>>(
            W_r, b_r, W_z, b_z, W_t, b_t, fea_in, fea_out, in_off, out_off,
            node_in, node_out, prop, (step == STEPS - 1) ? out : nullptr);
    }
}

// Round 7
// 413.703 us; speedup vs baseline: 1.5404x; 1.5404x over previous
//
#include <hip/hip_runtime.h>

#define N_NODES 50000
#define N_EDGES 100000
#define DD 32
#define STEPS 5
#define ETYPES 8
#define CAP_T 13312              // per-type slot capacity (mult of 64; mean 12500, sigma~105)
#define CAP (ETYPES * CAP_T)     // 106496 sorted slots
#define TRASH N_EDGES            // trash row index in fea arrays (extra row allocated)
#define SCAN_B 49                // 49 blocks * 1024 = 50176 >= N_NODES

#define NPT 4            // nodes per thread (gru)
#define NPB 128          // nodes per block (gru): 391 blocks
#define CAT_STRIDE 68    // floats per cat row: 64 (in|out) + 4 pad -> 17 float4

// prop[n,j] = emb[token[n],j]; zero cnt_in/cnt_out/tcnt; dummy-init sorted slots.
__global__ void init_kernel(const int* __restrict__ token,
                            const float* __restrict__ emb,
                            float* __restrict__ prop,
                            int* __restrict__ cnt,      // 2N+8: cnt_in | cnt_out | tcnt
                            int* __restrict__ se,
                            int* __restrict__ spi,
                            int* __restrict__ spo) {
    int idx = blockIdx.x * 256 + threadIdx.x;   // over N*D = 1.6M, exact grid
    int n = idx >> 5, j = idx & 31;
    prop[idx] = emb[token[n] * DD + j];
    if (idx < 2 * N_NODES + ETYPES) cnt[idx] = 0;
    if (idx < CAP) { se[idx] = 0; spi[idx] = TRASH; spo[idx] = TRASH; }
}

// One pass over edges: per-node ranks (global atomics) + type-bucket slot via
// block-local LDS histogram (one global atomic per type per block for the base).
__global__ void hist_kernel(const int* __restrict__ etype,
                            const int* __restrict__ src,
                            const int* __restrict__ dst,
                            int* __restrict__ cnt_in, int* __restrict__ cnt_out,
                            int* __restrict__ tcnt,
                            int* __restrict__ rank_in, int* __restrict__ rank_out,
                            int* __restrict__ qe) {
    __shared__ int lh[ETYPES], lbase[ETYPES];
    int tid = threadIdx.x;
    int e = blockIdx.x * 256 + tid;
    if (tid < ETYPES) lh[tid] = 0;
    __syncthreads();
    int t = 0, lr = 0;
    bool v = e < N_EDGES;
    if (v) {
        t = etype[e];
        lr = atomicAdd(&lh[t], 1);
        rank_in[e]  = atomicAdd(&cnt_in[dst[e]], 1);
        rank_out[e] = atomicAdd(&cnt_out[src[e]], 1);
    }
    __syncthreads();
    if (tid < ETYPES) lbase[tid] = atomicAdd(&tcnt[tid], lh[tid]);
    __syncthreads();
    if (v) qe[e] = t * CAP_T + lbase[t] + lr;
}

// Hierarchical scan stage 1: block-local exclusive scan (coalesced, wide).
__global__ __launch_bounds__(1024) void
scan1(const int* __restrict__ cnt_in, const int* __restrict__ cnt_out,
      int* __restrict__ off_in, int* __restrict__ off_out,
      int* __restrict__ bsum) {
    __shared__ int s[1024];
    int b = blockIdx.x;
    int ab = (b < SCAN_B) ? b : b - SCAN_B;
    const int* a = (b < SCAN_B) ? cnt_in : cnt_out;
    int* o = (b < SCAN_B) ? off_in : off_out;
    int i = ab * 1024 + threadIdx.x;
    int x = (i < N_NODES) ? a[i] : 0;
    s[threadIdx.x] = x;
    __syncthreads();
    for (int ofs = 1; ofs < 1024; ofs <<= 1) {
        int u = (threadIdx.x >= ofs) ? s[threadIdx.x - ofs] : 0;
        __syncthreads();
        s[threadIdx.x] += u;
        __syncthreads();
    }
    if (i < N_NODES) o[i] = s[threadIdx.x] - x;   // local exclusive
    if (threadIdx.x == 1023) bsum[b] = s[1023];
}

// Stage 2: scan 98 block sums. Since sum(cnt_in)=sum(cnt_out)=E exactly, one
// combined scan with a constant -E correction splits the two arrays.
__global__ void scan2(const int* __restrict__ bsum, int* __restrict__ ebase,
                      int* __restrict__ off_in, int* __restrict__ off_out) {
    __shared__ int s[128];
    int t = threadIdx.x;
    int x = (t < 2 * SCAN_B) ? bsum[t] : 0;
    s[t] = x;
    __syncthreads();
    for (int ofs = 1; ofs < 128; ofs <<= 1) {
        int u = (t >= ofs) ? s[t - ofs] : 0;
        __syncthreads();
        s[t] += u;
        __syncthreads();
    }
    if (t < SCAN_B) ebase[t] = s[t] - x;
    else if (t < 2 * SCAN_B) ebase[t] = s[t] - x - N_EDGES;
    if (t == 0) { off_in[N_NODES] = N_EDGES; off_out[N_NODES] = N_EDGES; }
}

// Stage 3: add scanned block bases.
__global__ __launch_bounds__(1024) void
scan3(int* __restrict__ off_in, int* __restrict__ off_out,
      const int* __restrict__ ebase) {
    int b = blockIdx.x;
    int ab = (b < SCAN_B) ? b : b - SCAN_B;
    int* o = (b < SCAN_B) ? off_in : off_out;
    int i = ab * 1024 + threadIdx.x;
    if (i < N_NODES) o[i] += ebase[b];
}

// Scatter edge records into type-sorted slots with final CSR positions.
__global__ void place_kernel(const int* __restrict__ src,
                             const int* __restrict__ dst,
                             const int* __restrict__ in_off,
                             const int* __restrict__ out_off,
                             const int* __restrict__ rank_in,
                             const int* __restrict__ rank_out,
                             const int* __restrict__ qe,
                             int* __restrict__ se, int* __restrict__ spi,
                             int* __restrict__ spo) {
    int e = blockIdx.x * 256 + threadIdx.x;
    if (e < N_EDGES) {
        int q = qe[e];
        int pi = in_off[dst[e]]  + rank_in[e];
        int po = out_off[src[e]] + rank_out[e];
        if (q < CAP) {                          // guard: never OOB even on 8-sigma
            se[q]  = src[e];
            spi[q] = pi;
            spo[q] = po;
        }
    }
}

// Wave = 16 same-type edges (two half-waves of 8). W column j lives in 64 VGPRs
// per lane for the whole wave: zero weight memory traffic in the inner loop.
__global__ __launch_bounds__(256) void
edge_kernel(const int* __restrict__ se, const int* __restrict__ spi,
            const int* __restrict__ spo, const float* __restrict__ W_edge,
            const float* __restrict__ prop,
            float* __restrict__ fea_in, float* __restrict__ fea_out) {
    int wid = blockIdx.x * 4 + (threadIdx.x >> 6);
    int lane = threadIdx.x & 63;
    int j = lane & 31;
    int slot0 = wid * 16 + ((lane >> 5) << 3);     // this half-wave's 8 slots
    int type = (wid * 16) / CAP_T;                 // wave-uniform (CAP_T % 16 == 0)
    const float2* Wt = (const float2*)W_edge + (size_t)type * (DD * DD);
    float2 w[DD];
#pragma unroll
    for (int i = 0; i < DD; ++i) w[i] = Wt[i * DD + j];   // 8KB once per wave
    int s[8], pi[8], po[8];
    float h[8];
#pragma unroll
    for (int k = 0; k < 8; ++k) {
        s[k] = se[slot0 + k]; pi[k] = spi[slot0 + k]; po[k] = spo[slot0 + k];
    }
#pragma unroll
    for (int k = 0; k < 8; ++k) h[k] = prop[(size_t)s[k] * DD + j];
    float aF[8] = {0.f,0.f,0.f,0.f,0.f,0.f,0.f,0.f};
    float aR[8] = {0.f,0.f,0.f,0.f,0.f,0.f,0.f,0.f};
#pragma unroll
    for (int i = 0; i < DD; ++i) {
#pragma unroll
        for (int k = 0; k < 8; ++k) {
            float hi = __shfl(h[k], i, 32);        // broadcast within half-wave
            aF[k] = fmaf(hi, w[i].x, aF[k]);
            aR[k] = fmaf(hi, w[i].y, aR[k]);
        }
    }
#pragma unroll
    for (int k = 0; k < 8; ++k) {
        fea_in [(size_t)pi[k] * DD + j] = aF[k];   // plain 128B-row stores
        fea_out[(size_t)po[k] * DD + j] = aR[k];
    }
}

__device__ __forceinline__ void fma4(float (&acc)[4], float c, const float4& w) {
    acc[0] = fmaf(c, w.x, acc[0]);
    acc[1] = fmaf(c, w.y, acc[1]);
    acc[2] = fmaf(c, w.z, acc[2]);
    acc[3] = fmaf(c, w.w, acc[3]);
}
__device__ __forceinline__ float sigm(float x) {
    return 1.f / (1.f + __expf(-x));
}
__device__ __forceinline__ float fast_tanh(float x) {
    x = fminf(fmaxf(x, -15.f), 15.f);
    float e = __expf(2.f * x);
    return (e - 1.f) / (e + 1.f);
}

// Block = 256 threads = 128 nodes (NPT=4, the proven R3 shape). Weights staged
// to LDS once per block (36.9 KB; kills the L1 weight-reload bottleneck that
// tracked gru time across rounds); cat holds in|out only (34.8 KB, stride 68);
// prop in registers with the matvec (node,quad) mapping; rows 64-95 of each
// matvec use 8-lane shfl broadcast. Per-node CSR gather (no atomics, no zero
// pass). One __syncthreads total. LDS 71.7 KB -> 2 blocks/CU (grid is 391
// blocks = 1.5 blocks/CU anyway, so the LDS cost is free).
__global__ __launch_bounds__(256) void
gru_kernel(const float* __restrict__ W_r, const float* __restrict__ b_r,
           const float* __restrict__ W_z, const float* __restrict__ b_z,
           const float* __restrict__ W_t, const float* __restrict__ b_t,
           const float* __restrict__ fea_in,
           const float* __restrict__ fea_out,
           const int* __restrict__ in_off,
           const int* __restrict__ out_off,
           float* __restrict__ prop,
           float* __restrict__ out2) {
    __shared__ float cat[NPB * CAT_STRIDE];           // 34.8 KB
    __shared__ float4 wlds[3 * 96 * 8];               // 36.9 KB: W_r|W_z|W_t
    float4* cat4 = (float4*)cat;                      // row stride 17 float4
    const int tid = threadIdx.x;
    const int n0 = blockIdx.x * NPB;
    const int jq = tid & 7;
    const int ng = tid >> 3;

    // ---- stage weights -> LDS (9 float4 loads/thread, coalesced) ----
    {
        const float4* wr4 = (const float4*)W_r;       // 768 float4 each
        const float4* wz4 = (const float4*)W_z;
        const float4* wt4 = (const float4*)W_t;
#pragma unroll
        for (int q = 0; q < 3; ++q) {
            int i = q * 256 + tid;
            wlds[i]        = wr4[i];
            wlds[768 + i]  = wz4[i];
            wlds[1536 + i] = wt4[i];
        }
    }
    // ---- prop -> registers (thread mapping == matvec mapping) ----
    float p_[NPT][4];
    {
        const float4* p4 = (const float4*)(prop + (size_t)n0 * DD);
        const float4 zz = {0.f, 0.f, 0.f, 0.f};
#pragma unroll
        for (int k = 0; k < NPT; ++k) {
            int f = k * 256 + tid;                    // node = f>>3, quad jq
            float4 p = (n0 + (f >> 3) < N_NODES) ? p4[f] : zz;
            p_[k][0] = p.x; p_[k][1] = p.y; p_[k][2] = p.z; p_[k][3] = p.w;
        }
    }
    // ---- per-node CSR gather of in/out segment sums (exclusive writes) ----
    {
        const float4* fi4 = (const float4*)fea_in;    // row = 8 float4
        const float4* fo4 = (const float4*)fea_out;
        const float4 zz = {0.f, 0.f, 0.f, 0.f};
#pragma unroll
        for (int q = 0; q < 4; ++q) {
            int f = q * 256 + tid;                    // (node,c4) pair
            int node = f >> 3;
            int c4 = f & 7;
            int gn = n0 + node;
            float4 va = zz, vb = zz;
            if (gn < N_NODES) {
                int i0 = in_off[gn], i1 = in_off[gn + 1];
                for (int r = i0; r < i1; ++r) {
                    float4 x = fi4[(size_t)r * 8 + c4];
                    va.x += x.x; va.y += x.y; va.z += x.z; va.w += x.w;
                }
                int o0 = out_off[gn], o1 = out_off[gn + 1];
                for (int r = o0; r < o1; ++r) {
                    float4 x = fo4[(size_t)r * 8 + c4];
                    vb.x += x.x; vb.y += x.y; vb.z += x.z; vb.w += x.w;
                }
            }
            cat4[node * 17 + c4]     = va;
            cat4[node * 17 + 8 + c4] = vb;
        }
    }
    __syncthreads();

    // ---- phase A: r,z (weights from LDS) ----
    float r_[NPT][4], z_[NPT][4];
    {
        float4 br = ((const float4*)b_r)[jq];
        float4 bz = ((const float4*)b_z)[jq];
#pragma unroll
        for (int k = 0; k < NPT; ++k) {
            r_[k][0] = br.x; r_[k][1] = br.y; r_[k][2] = br.z; r_[k][3] = br.w;
            z_[k][0] = bz.x; z_[k][1] = bz.y; z_[k][2] = bz.z; z_[k][3] = bz.w;
        }
    }
    // rows 0..63: in|out from cat LDS
#pragma unroll 1
    for (int g = 0; g < 16; ++g) {
        int m0 = g * 4;
        float4 wr[4], wz[4];
#pragma unroll
        for (int i = 0; i < 4; ++i) {
            wr[i] = wlds[(m0 + i) * 8 + jq];
            wz[i] = wlds[768 + (m0 + i) * 8 + jq];
        }
#pragma unroll
        for (int k = 0; k < NPT; ++k) {
            float4 c = cat4[(ng + 32 * k) * 17 + g];
            fma4(r_[k], c.x, wr[0]); fma4(r_[k], c.y, wr[1]);
            fma4(r_[k], c.z, wr[2]); fma4(r_[k], c.w, wr[3]);
            fma4(z_[k], c.x, wz[0]); fma4(z_[k], c.y, wz[1]);
            fma4(z_[k], c.z, wz[2]); fma4(z_[k], c.w, wz[3]);
        }
    }
    // rows 64..95: prop via 8-lane shfl broadcast
#pragma unroll 1
    for (int i2 = 0; i2 < 8; ++i2) {
        float4 wr[4], wz[4];
#pragma unroll
        for (int c = 0; c < 4; ++c) {
            wr[c] = wlds[(64 + i2 * 4 + c) * 8 + jq];
            wz[c] = wlds[768 + (64 + i2 * 4 + c) * 8 + jq];
        }
#pragma unroll
        for (int k = 0; k < NPT; ++k) {
            float pc0 = __shfl(p_[k][0], i2, 8);
            float pc1 = __shfl(p_[k][1], i2, 8);
            float pc2 = __shfl(p_[k][2], i2, 8);
            float pc3 = __shfl(p_[k][3], i2, 8);
            fma4(r_[k], pc0, wr[0]); fma4(r_[k], pc1, wr[1]);
            fma4(r_[k], pc2, wr[2]); fma4(r_[k], pc3, wr[3]);
            fma4(z_[k], pc0, wz[0]); fma4(z_[k], pc1, wz[1]);
            fma4(z_[k], pc2, wz[2]); fma4(z_[k], pc3, wz[3]);
        }
    }

#pragma unroll
    for (int k = 0; k < NPT; ++k)
#pragma unroll
        for (int j = 0; j < 4; ++j) {
            r_[k][j] = sigm(r_[k][j]) * p_[k][j];     // r := r*p
            z_[k][j] = sigm(z_[k][j]);
        }

    // ---- phase B: t (weights from LDS) ----
    float t_[NPT][4];
    {
        float4 bt = ((const float4*)b_t)[jq];
#pragma unroll
        for (int k = 0; k < NPT; ++k) {
            t_[k][0] = bt.x; t_[k][1] = bt.y; t_[k][2] = bt.z; t_[k][3] = bt.w;
        }
    }
#pragma unroll 1
    for (int g = 0; g < 16; ++g) {
        int m0 = g * 4;
        float4 wt[4];
#pragma unroll
        for (int i = 0; i < 4; ++i)
            wt[i] = wlds[1536 + (m0 + i) * 8 + jq];
#pragma unroll
        for (int k = 0; k < NPT; ++k) {
            float4 c = cat4[(ng + 32 * k) * 17 + g];
            fma4(t_[k], c.x, wt[0]); fma4(t_[k], c.y, wt[1]);
            fma4(t_[k], c.z, wt[2]); fma4(t_[k], c.w, wt[3]);
        }
    }
    // rows 64..95: r*p via 8-lane shfl broadcast
#pragma unroll 1
    for (int i2 = 0; i2 < 8; ++i2) {
        float4 wt[4];
#pragma unroll
        for (int c = 0; c < 4; ++c)
            wt[c] = wlds[1536 + (64 + i2 * 4 + c) * 8 + jq];
#pragma unroll
        for (int k = 0; k < NPT; ++k) {
            float rc0 = __shfl(r_[k][0], i2, 8);
            float rc1 = __shfl(r_[k][1], i2, 8);
            float rc2 = __shfl(r_[k][2], i2, 8);
            float rc3 = __shfl(r_[k][3], i2, 8);
            fma4(t_[k], rc0, wt[0]); fma4(t_[k], rc1, wt[1]);
            fma4(t_[k], rc2, wt[2]); fma4(t_[k], rc3, wt[3]);
        }
    }

    // ---- update: prop = p + z*(tanh(t) - p); final step also writes out2 ----
#pragma unroll
    for (int k = 0; k < NPT; ++k) {
        int node = n0 + ng + 32 * k;
        if (node < N_NODES) {
            float4 o;
            o.x = fmaf(z_[k][0], fast_tanh(t_[k][0]) - p_[k][0], p_[k][0]);
            o.y = fmaf(z_[k][1], fast_tanh(t_[k][1]) - p_[k][1], p_[k][1]);
            o.z = fmaf(z_[k][2], fast_tanh(t_[k][2]) - p_[k][2], p_[k][2]);
            o.w = fmaf(z_[k][3], fast_tanh(t_[k][3]) - p_[k][3], p_[k][3]);
            ((float4*)(prop + (size_t)node * DD))[jq] = o;
            if (out2) ((float4*)(out2 + (size_t)node * DD))[jq] = o;
        }
    }
}

extern "C" void kernel_launch(void* const* d_in, const int* in_sizes, int n_in,
                              void* d_out, int out_size, void* d_ws, size_t ws_size,
                              hipStream_t stream) {
    const int*   token  = (const int*)d_in[0];
    const int*   etype  = (const int*)d_in[1];
    const int*   src    = (const int*)d_in[2];
    const int*   dst    = (const int*)d_in[3];
    const float* emb    = (const float*)d_in[4];
    const float* W_edge = (const float*)d_in[5];
    const float* W_r    = (const float*)d_in[6];
    const float* b_r    = (const float*)d_in[7];
    const float* W_z    = (const float*)d_in[8];
    const float* b_z    = (const float*)d_in[9];
    const float* W_t    = (const float*)d_in[10];
    const float* b_t    = (const float*)d_in[11];
    float* out = (float*)d_out;

    // Persistent workspace (~33 MB; ws_size = 256 MB per the poison fill):
    float* prop    = (float*)d_ws;                            // N*D
    float* fea_in  = prop    + (size_t)N_NODES * DD;          // (E+1)*D
    float* fea_out = fea_in  + (size_t)(N_EDGES + 1) * DD;    // (E+1)*D
    int* in_off   = (int*)(fea_out + (size_t)(N_EDGES + 1) * DD); // N+1
    int* out_off  = in_off + (N_NODES + 1);                   // N+1
    int* se       = out_off + (N_NODES + 1);                  // CAP
    int* spi      = se + CAP;                                 // CAP
    int* spo      = spi + CAP;                                // CAP

    // Setup temporaries OVERLAID on fea_in (dead before first edge_kernel
    // write; step loop never reads them).
    int* cnt      = (int*)fea_in;                             // 2N+8
    int* cnt_in   = cnt;
    int* cnt_out  = cnt + N_NODES;
    int* tcnt     = cnt + 2 * N_NODES;
    int* rank_in  = cnt + 2 * N_NODES + ETYPES;               // E
    int* rank_out = rank_in + N_EDGES;                        // E
    int* qe       = rank_out + N_EDGES;                       // E
    int* bsum     = qe + N_EDGES;                             // 2*SCAN_B
    int* ebase    = bsum + 2 * SCAN_B;                        // 2*SCAN_B

    // per-launch setup: prop init + type-bucketed CSR build
    init_kernel<<<(N_NODES * DD) / 256, 256, 0, stream>>>(token, emb, prop, cnt,
                                                          se, spi, spo);
    hist_kernel<<<(N_EDGES + 255) / 256, 256, 0, stream>>>(
        etype, src, dst, cnt_in, cnt_out, tcnt, rank_in, rank_out, qe);
    scan1<<<2 * SCAN_B, 1024, 0, stream>>>(cnt_in, cnt_out, in_off, out_off, bsum);
    scan2<<<1, 128, 0, stream>>>(bsum, ebase, in_off, out_off);
    scan3<<<2 * SCAN_B, 1024, 0, stream>>>(in_off, out_off, ebase);
    place_kernel<<<(N_EDGES + 255) / 256, 256, 0, stream>>>(
        src, dst, in_off, out_off, rank_in, rank_out, qe, se, spi, spo);

    for (int step = 0; step < STEPS; ++step) {
        edge_kernel<<<CAP / 64, 256, 0, stream>>>(se, spi, spo, W_edge, prop,
                                                  fea_in, fea_out);
        gru_kernel<<<(N_NODES + NPB - 1) / NPB, 256, 0, stream>>>(
            W_r, b_r, W_z, b_z, W_t, b_t, fea_in, fea_out, in_off, out_off,
            prop, (step == STEPS - 1) ? out : nullptr);
    }
}